// Round 5
// baseline (155.460 us; speedup 1.0000x reference)
//
#include <hip/hip_runtime.h>

typedef _Float16 half_t;
typedef half_t f16x8 __attribute__((ext_vector_type(8)));
typedef float f32x4 __attribute__((ext_vector_type(4)));

#define LOG2E 1.44269504088896340736f

// Problem dims (fixed)
#define NROWS 65536
#define DIN   64
#define NCTRS 1024
#define DOUT  256

// Workspace layout (bytes). ONE FRAGMENT = 64 lanes x 16 B = 1024 B.
#define CSWZ_OFF 0
#define CSWZ_BYTES (128 * 1024)
#define VSWZ_OFF (CSWZ_OFF + CSWZ_BYTES)            // 131072
#define VSWZ_BYTES (512 * 1024)
#define CSQ_OFF  (VSWZ_OFF + VSWZ_BYTES)            // 655360; end 659456

#define VT_STRIDE 260   // 256 + 4 pad
#define CT_STRIDE 68

typedef __attribute__((address_space(1))) const void* gas_ptr;
typedef __attribute__((address_space(3))) void* las_ptr;

// async global->LDS DMA: wave-uniform LDS base, HW scatters lane i at +16*i.
__device__ __forceinline__ void gld_lds16(const half_t* gp, half_t* lp) {
  __builtin_amdgcn_global_load_lds((gas_ptr)gp, (las_ptr)lp, 16, 0, 0);
}

// ---------------------------------------------------------------------------
// Precompute (unchanged from R4, proven): one block per 32-center chunk.
// Fragment layout (A/B symmetric): lane holds [idx=lane&15][k=8*(lane>>4)+j].
// ---------------------------------------------------------------------------
__global__ __launch_bounds__(256) void precompute_kernel(
    const float* __restrict__ ctrs, const float* __restrict__ values,
    const float* __restrict__ s, char* __restrict__ ws) {
  half_t* Cswz = (half_t*)(ws + CSWZ_OFF);
  half_t* Vswz = (half_t*)(ws + VSWZ_OFF);
  float* csq2 = (float*)(ws + CSQ_OFF);

  __shared__ half_t Vt[32 * VT_STRIDE];
  __shared__ half_t Ct[32 * CT_STRIDE];

  const int c = blockIdx.x, tid = threadIdx.x;

  for (int i = tid; i < 32 * 256; i += 256) {
    int r = i >> 8, col = i & 255;
    Vt[r * VT_STRIDE + col] = (half_t)values[(c * 32 + r) * DOUT + col];
  }
  for (int i = tid; i < 32 * 64; i += 256) {
    int r = i >> 6, col = i & 63;
    Ct[r * CT_STRIDE + col] = (half_t)ctrs[(c * 32 + r) * DIN + col];
  }
  if (tid < 32) {
    int k = c * 32 + tid;
    float acc = 0.0f;
    for (int d = 0; d < DIN; ++d) {
      float cv = ctrs[k * DIN + d];
      acc = fmaf(cv * cv, s[d], acc);
    }
    csq2[k] = acc * LOG2E;
  }
  __syncthreads();

  const int w = tid >> 6, l = tid & 63, l4 = l >> 4, lm = l & 15;

  {  // Cswz frag f = w; ct = f>>1, kt = f&1
    int ct = w >> 1, kt = w & 1;
    f16x8 v;
#pragma unroll
    for (int j = 0; j < 8; ++j)
      v[j] = Ct[(ct * 16 + lm) * CT_STRIDE + kt * 32 + l4 * 8 + j];
    *(f16x8*)(Cswz + ((c * 4 + w) * 64 + l) * 8) = v;
  }
#pragma unroll
  for (int q = 0; q < 4; ++q) {  // Vswz: 16 frags, 4 per wave
    int sl = w * 4 + q;
    f16x8 v;
#pragma unroll
    for (int j = 0; j < 8; ++j)
      v[j] = Vt[(l4 * 8 + j) * VT_STRIDE + sl * 16 + lm];
    *(f16x8*)(Vswz + ((c * 16 + sl) * 64 + l) * 8) = v;
  }
}

// ---------------------------------------------------------------------------
// Fused kernel, two-pass softmax + LDS operand staging:
//   B-operands (C frags, V frags) DMA'd global->LDS once per BLOCK per chunk
//   (double-buffered, 1 barrier/chunk) and read by all 4 waves -> L2 traffic
//   /4 vs R4; LDS delivers ~256 B/cyc/CU vs L2's ~56.
// Block = 128 rows (4 waves x 32) x 256 cols. scores=(2*cross-csq)*log2e.
// ---------------------------------------------------------------------------
__global__ __launch_bounds__(256, 2) void attn_kernel(
    const float* __restrict__ x, const float* __restrict__ s,
    const char* __restrict__ ws, float* __restrict__ out) {
  const half_t* Cswz = (const half_t*)(ws + CSWZ_OFF);
  const half_t* Vswz = (const half_t*)(ws + VSWZ_OFF);
  const float* csq2 = (const float*)(ws + CSQ_OFF);

  __shared__ half_t Vbuf[2][16 * 512];   // 2 x 16 KB
  __shared__ half_t Cbuf[2][4 * 512];    // 2 x 4 KB
  __shared__ half_t Plds[4 * 32 * 40];   // 10 KB, wave-private regions
  __shared__ float csq_l[NCTRS];         // 4 KB

  const int tid = threadIdx.x;
  const int w = tid >> 6, l = tid & 63, l4 = l >> 4, lm = l & 15;
  const int rowbase = blockIdx.x * 128 + w * 32;

  // stage csq2 -> LDS once (drained by the first barrier below)
  *(f32x4*)(csq_l + tid * 4) = *(const f32x4*)(csq2 + tid * 4);

  // ---- A fragments (x*s -> f16) in registers, loaded once
  f16x8 A[2][2];
#pragma unroll
  for (int rt = 0; rt < 2; ++rt) {
#pragma unroll
    for (int kt = 0; kt < 2; ++kt) {
      int din = kt * 32 + l4 * 8;
      const float* src = x + (rowbase + rt * 16 + lm) * DIN + din;
      f16x8 a;
#pragma unroll
      for (int j = 0; j < 8; ++j) a[j] = (half_t)(src[j] * s[din + j]);
      A[rt][kt] = a;
    }
  }

  // ---- all-ones B column tile (col 0), lane-constant
  f16x8 ones;
#pragma unroll
  for (int j = 0; j < 8; ++j) ones[j] = (lm == 0) ? (half_t)1.0f : (half_t)0.0f;

  // ================= PASS 1: row max =================
  float m[2][4];
#pragma unroll
  for (int rt = 0; rt < 2; ++rt)
#pragma unroll
    for (int j = 0; j < 4; ++j) m[rt][j] = -1e30f;

  // prologue DMA: chunk 0 C frags (wave w stages frag w)
  gld_lds16(Cswz + (0 * 4 + w) * 512 + l * 8, &Cbuf[0][w * 512]);

  for (int c = 0; c < 32; ++c) {
    __syncthreads();  // drains this chunk's DMA; protects buffer re-use
    if (c + 1 < 32)
      gld_lds16(Cswz + ((c + 1) * 4 + w) * 512 + l * 8,
                &Cbuf[(c + 1) & 1][w * 512]);
    const half_t* cb = Cbuf[c & 1];
    f16x8 b0 = *(const f16x8*)(cb + 0 * 512 + l * 8);
    f16x8 b1 = *(const f16x8*)(cb + 1 * 512 + l * 8);
    f16x8 b2 = *(const f16x8*)(cb + 2 * 512 + l * 8);
    f16x8 b3 = *(const f16x8*)(cb + 3 * 512 + l * 8);
    float cs0 = csq_l[c * 32 + lm], cs1 = csq_l[c * 32 + 16 + lm];
#pragma unroll
    for (int rt = 0; rt < 2; ++rt) {
      f32x4 a0 = {0.f, 0.f, 0.f, 0.f}, a1 = {0.f, 0.f, 0.f, 0.f};
      a0 = __builtin_amdgcn_mfma_f32_16x16x32_f16(A[rt][0], b0, a0, 0, 0, 0);
      a0 = __builtin_amdgcn_mfma_f32_16x16x32_f16(A[rt][1], b1, a0, 0, 0, 0);
      a1 = __builtin_amdgcn_mfma_f32_16x16x32_f16(A[rt][0], b2, a1, 0, 0, 0);
      a1 = __builtin_amdgcn_mfma_f32_16x16x32_f16(A[rt][1], b3, a1, 0, 0, 0);
#pragma unroll
      for (int j = 0; j < 4; ++j) {
        float v0 = fmaf(a0[j], 2.0f * LOG2E, -cs0);
        float v1 = fmaf(a1[j], 2.0f * LOG2E, -cs1);
        m[rt][j] = fmaxf(m[rt][j], fmaxf(v0, v1));
      }
    }
  }
  // per-lane maxima -> exact row max (rows live in 16-lane groups)
#pragma unroll
  for (int rt = 0; rt < 2; ++rt)
#pragma unroll
    for (int j = 0; j < 4; ++j) {
      float v = m[rt][j];
      v = fmaxf(v, __shfl_xor(v, 1));
      v = fmaxf(v, __shfl_xor(v, 2));
      v = fmaxf(v, __shfl_xor(v, 4));
      v = fmaxf(v, __shfl_xor(v, 8));
      m[rt][j] = v;
    }

  // ================= PASS 2: exp + PV =================
  f32x4 O[2][16];
  f32x4 L[2];
#pragma unroll
  for (int rt = 0; rt < 2; ++rt) {
    L[rt] = (f32x4){0.f, 0.f, 0.f, 0.f};
#pragma unroll
    for (int u = 0; u < 16; ++u) O[rt][u] = (f32x4){0.f, 0.f, 0.f, 0.f};
  }

  half_t* pw = Plds + w * (32 * 40);  // wave-private P region

  // prologue DMA: chunk 0 C + V (wave w stages C frag w, V frags w*4..w*4+3)
  gld_lds16(Cswz + (0 * 4 + w) * 512 + l * 8, &Cbuf[0][w * 512]);
#pragma unroll
  for (int q = 0; q < 4; ++q)
    gld_lds16(Vswz + (0 * 16 + w * 4 + q) * 512 + l * 8,
              &Vbuf[0][(w * 4 + q) * 512]);

  for (int c = 0; c < 32; ++c) {
    __syncthreads();  // drains this chunk's DMA; protects buffer re-use
    if (c + 1 < 32) {
      gld_lds16(Cswz + ((c + 1) * 4 + w) * 512 + l * 8,
                &Cbuf[(c + 1) & 1][w * 512]);
#pragma unroll
      for (int q = 0; q < 4; ++q)
        gld_lds16(Vswz + ((c + 1) * 16 + w * 4 + q) * 512 + l * 8,
                  &Vbuf[(c + 1) & 1][(w * 4 + q) * 512]);
    }
    const half_t* cb = Cbuf[c & 1];
    const half_t* vf = Vbuf[c & 1];
    f16x8 b0 = *(const f16x8*)(cb + 0 * 512 + l * 8);
    f16x8 b1 = *(const f16x8*)(cb + 1 * 512 + l * 8);
    f16x8 b2 = *(const f16x8*)(cb + 2 * 512 + l * 8);
    f16x8 b3 = *(const f16x8*)(cb + 3 * 512 + l * 8);
    float cs0 = csq_l[c * 32 + lm], cs1 = csq_l[c * 32 + 16 + lm];
    f16x8 pa[2];
#pragma unroll
    for (int rt = 0; rt < 2; ++rt) {
      f32x4 a0 = {0.f, 0.f, 0.f, 0.f}, a1 = {0.f, 0.f, 0.f, 0.f};
      a0 = __builtin_amdgcn_mfma_f32_16x16x32_f16(A[rt][0], b0, a0, 0, 0, 0);
      a0 = __builtin_amdgcn_mfma_f32_16x16x32_f16(A[rt][1], b1, a0, 0, 0, 0);
      a1 = __builtin_amdgcn_mfma_f32_16x16x32_f16(A[rt][0], b2, a1, 0, 0, 0);
      a1 = __builtin_amdgcn_mfma_f32_16x16x32_f16(A[rt][1], b3, a1, 0, 0, 0);
#pragma unroll
      for (int j = 0; j < 4; ++j) {
        // bitwise-identical recompute of pass-1 scores => s - m <= 0
        float v0 = fmaf(a0[j], 2.0f * LOG2E, -cs0) - m[rt][j];
        float v1 = fmaf(a1[j], 2.0f * LOG2E, -cs1) - m[rt][j];
        float p0 = __builtin_amdgcn_exp2f(v0);
        float p1 = __builtin_amdgcn_exp2f(v1);
        int pr = (rt * 16 + l4 * 4 + j) * 40 + lm;
        pw[pr] = (half_t)p0;
        pw[pr + 16] = (half_t)p1;
      }
      // P back as A-operand (same-wave LDS; compiler orders via lgkmcnt)
      pa[rt] = *(const f16x8*)(pw + (rt * 16 + lm) * 40 + l4 * 8);
    }
#pragma unroll
    for (int u = 0; u < 16; ++u) {
      f16x8 vb = *(const f16x8*)(vf + u * 512 + l * 8);
      O[0][u] = __builtin_amdgcn_mfma_f32_16x16x32_f16(pa[0], vb, O[0][u], 0, 0, 0);
      O[1][u] = __builtin_amdgcn_mfma_f32_16x16x32_f16(pa[1], vb, O[1][u], 0, 0, 0);
    }
    L[0] = __builtin_amdgcn_mfma_f32_16x16x32_f16(pa[0], ones, L[0], 0, 0, 0);
    L[1] = __builtin_amdgcn_mfma_f32_16x16x32_f16(pa[1], ones, L[1], 0, 0, 0);
  }

  // ---- epilogue: normalize (row sum = col 0 of L tile, lanes lm==0)
#pragma unroll
  for (int rt = 0; rt < 2; ++rt) {
#pragma unroll
    for (int j = 0; j < 4; ++j) {
      float lv = __shfl(L[rt][j], l & 48);  // broadcast from lane 16*l4
      float inv = 1.0f / fmaxf(lv, 1e-30f);
      int row = rowbase + rt * 16 + l4 * 4 + j;
      float* po = out + row * DOUT + lm;
#pragma unroll
      for (int ct = 0; ct < 16; ++ct) po[ct * 16] = O[rt][ct][j] * inv;
    }
  }
}

extern "C" void kernel_launch(void* const* d_in, const int* in_sizes, int n_in,
                              void* d_out, int out_size, void* d_ws, size_t ws_size,
                              hipStream_t stream) {
  const float* x = (const float*)d_in[0];
  const float* ctrs = (const float*)d_in[1];
  const float* values = (const float*)d_in[2];
  const float* s = (const float*)d_in[3];
  float* out = (float*)d_out;
  char* ws = (char*)d_ws;

  hipLaunchKernelGGL(precompute_kernel, dim3(32), dim3(256), 0, stream,
                     ctrs, values, s, ws);
  hipLaunchKernelGGL(attn_kernel, dim3(512), dim3(256), 0, stream,
                     x, s, ws, out);
}